// Round 4
// baseline (324.408 us; speedup 1.0000x reference)
//
#include <hip/hip_runtime.h>
#include <math.h>

#define DD 8
#define BB 4096
#define VV 1024
#define K_SEL 102
#define RPB 4            // rows (waves) per block

typedef float fx4 __attribute__((ext_vector_type(4)));   // native vec for nontemporal store

// order-preserving float <-> uint key maps (bijective, exact)
__device__ __forceinline__ unsigned f2key(float f) {
    unsigned u = __float_as_uint(f);
    unsigned m = (unsigned)((int)u >> 31) | 0x80000000u;  // neg: FFFFFFFF, pos: 80000000
    return u ^ m;
}
__device__ __forceinline__ float key2f(unsigned k) {
    unsigned m = 0x80000000u | ~((unsigned)((int)k >> 31));
    return __uint_as_float(k ^ m);
}

// One WAVE per (d,b) row: 16 elems/lane, wave-private LDS histogram, no __syncthreads.
__global__ __launch_bounds__(256) void decode_row_kernel(
    const float* __restrict__ logits,
    const float* __restrict__ unoise,
    const int* __restrict__ curvals,
    float* __restrict__ probs_out,   // [D*B*V]
    int* __restrict__ samples)       // [D*B] workspace
{
    const int wave = threadIdx.x >> 6;
    const int lane = threadIdx.x & 63;
    const int row  = blockIdx.x * RPB + wave;

    // pass 0: 4 replica histograms (stride 260 dwords -> bank-shifted); passes>=1: replica 0 only
    __shared__ __align__(16) unsigned hist[RPB][1040];
    unsigned* h = hist[wave];

    const float4* l4 = (const float4*)(logits + (size_t)row * VV);
    const float4* u4 = (const float4*)(unoise + (size_t)row * VV);
    const int cv = curvals[row];

    // ---- load + mask -> floats + order keys ----
    float x[16];
    unsigned key[16];
    {
        // only v<16 can be masked (cv<16, v==0): all in the i==0 chunk, lanes 0..3
        float4 f = l4[lane];
        const int vb = lane * 4;
        float e[4] = {f.x, f.y, f.z, f.w};
#pragma unroll
        for (int j = 0; j < 4; j++) {
            int v = vb + j;
            float t = (v < cv || v == 0) ? -INFINITY : e[j];
            x[j] = t;
            key[j] = f2key(t);
        }
    }
#pragma unroll
    for (int i = 1; i < 4; i++) {
        float4 f = l4[i * 64 + lane];
        float e[4] = {f.x, f.y, f.z, f.w};
#pragma unroll
        for (int j = 0; j < 4; j++) {
            x[i * 4 + j] = e[j];
            key[i * 4 + j] = f2key(e[j]);
        }
    }

    // ---- exact radix select (MSB-first, 8 bits/pass) with early termination ----
    unsigned prefix = 0;
    unsigned kk = K_SEL;
    unsigned kthkey = 0;
    bool done = false;
    const int rep = (lane & 3) * 260;
#pragma unroll
    for (int pass = 0; pass < 4; pass++) {
        if (!done) {
            const int shift = 24 - 8 * pass;
            const uint4 z = {0u, 0u, 0u, 0u};
            if (pass == 0) {
#pragma unroll
                for (int r = 0; r < 4; r++)
                    ((uint4*)(h + r * 260))[lane] = z;
            } else {
                ((uint4*)h)[lane] = z;
            }
            __builtin_amdgcn_wave_barrier();
            const unsigned base = (pass == 0) ? (unsigned)rep : 0u;
#pragma unroll
            for (int i = 0; i < 16; i++) {
                bool act = (pass == 0) ||
                           (((key[i] ^ prefix) >> ((shift + 8) & 31)) == 0);
                if (act) atomicAdd(h + base + ((key[i] >> shift) & 0xFFu), 1u);
            }
            __builtin_amdgcn_wave_barrier();
            unsigned cnt0, cnt1, cnt2, cnt3;
            if (pass == 0) {
                uint4 c0 = ((uint4*)(h + 0 * 260))[lane];
                uint4 c1 = ((uint4*)(h + 1 * 260))[lane];
                uint4 c2 = ((uint4*)(h + 2 * 260))[lane];
                uint4 c3 = ((uint4*)(h + 3 * 260))[lane];
                cnt0 = c0.x + c1.x + c2.x + c3.x;
                cnt1 = c0.y + c1.y + c2.y + c3.y;
                cnt2 = c0.z + c1.z + c2.z + c3.z;
                cnt3 = c0.w + c1.w + c2.w + c3.w;
            } else {
                uint4 c = ((uint4*)h)[lane];
                cnt0 = c.x; cnt1 = c.y; cnt2 = c.z; cnt3 = c.w;
            }
            __builtin_amdgcn_wave_barrier();
            // local suffix over lane's 4 digits, then wave suffix scan of totals
            unsigned s3 = cnt3;
            unsigned s2 = cnt2 + s3;
            unsigned s1 = cnt1 + s2;
            unsigned s0 = cnt0 + s1;
            unsigned suf = s0;
#pragma unroll
            for (int off = 1; off < 64; off <<= 1) {
                unsigned o = __shfl_down(suf, off, 64);
                suf += (lane + off < 64) ? o : 0u;
            }
            const unsigned above = suf - s0;
            // locate the digit with gt < kk <= ge; pack (digit, cnt, kk_new)
            unsigned sel = 0u;
            bool found = false;
            unsigned ge, gt;
            ge = s0 + above; gt = ge - cnt0;
            if (ge >= kk && gt < kk) { found = true; sel = ((unsigned)(lane * 4 + 0) << 22) | (cnt0 << 11) | (kk - gt); }
            ge = s1 + above; gt = ge - cnt1;
            if (ge >= kk && gt < kk) { found = true; sel = ((unsigned)(lane * 4 + 1) << 22) | (cnt1 << 11) | (kk - gt); }
            ge = s2 + above; gt = ge - cnt2;
            if (ge >= kk && gt < kk) { found = true; sel = ((unsigned)(lane * 4 + 2) << 22) | (cnt2 << 11) | (kk - gt); }
            ge = s3 + above; gt = ge - cnt3;
            if (ge >= kk && gt < kk) { found = true; sel = ((unsigned)(lane * 4 + 3) << 22) | (cnt3 << 11) | (kk - gt); }
            unsigned long long bal = __ballot(found);
            int src = __ffsll((unsigned long long)bal) - 1;
            sel = __shfl(sel, src, 64);
            const unsigned digit = sel >> 22;
            const unsigned cnt   = (sel >> 11) & 0x7FFu;
            const unsigned k2    = sel & 0x7FFu;
            prefix |= digit << shift;
            if (pass == 3) {
                kthkey = prefix;
                done = true;
            } else if (k2 == cnt || k2 == 1u) {
                // kth is the min (k2==cnt) or max (k2==1) of the selected bin: exact,
                // via max-reduce in (conditionally complemented) key space.
                const unsigned xm = (k2 == cnt) ? 0xFFFFFFFFu : 0u;
                unsigned ext = 0u;
#pragma unroll
                for (int i = 0; i < 16; i++) {
                    bool m2 = (((key[i] ^ prefix) >> shift) == 0);
                    unsigned t = key[i] ^ xm;
                    if (m2) ext = max(ext, t);
                }
#pragma unroll
                for (int off = 32; off; off >>= 1)
                    ext = max(ext, (unsigned)__shfl_xor(ext, off, 64));
                kthkey = ext ^ xm;
                done = true;
            } else {
                kk = k2;
            }
            __builtin_amdgcn_wave_barrier();
        }
    }
    const float kthf = key2f(kthkey);   // finite threshold; x >= kthf <=> key >= kthkey

    // ---- row max (float space, butterfly) ----
    float m = x[0];
#pragma unroll
    for (int i = 1; i < 16; i++) m = fmaxf(m, x[i]);
#pragma unroll
    for (int off = 32; off; off >>= 1)
        m = fmaxf(m, __shfl_xor(m, off, 64));

    // ---- sum of exp over kept elements ----
    float ex[16];
    float s = 0.0f;
#pragma unroll
    for (int i = 0; i < 16; i++) {
        bool keep = x[i] >= kthf;
        float e = keep ? __expf(x[i] - m) : 0.0f;
        ex[i] = e;
        s += e;
    }
#pragma unroll
    for (int off = 32; off; off >>= 1)
        s += __shfl_xor(s, off, 64);

    const float lz  = __logf(s);
    const float inv = 1.0f / s;
    const float mlz = m + lz;

    // ---- probs write (nontemporal stream) + gumbel-max argmax ----
    float bestv = -INFINITY;
    int   besti = VV;
    fx4* p4 = (fx4*)(probs_out + (size_t)row * VV);
#pragma unroll
    for (int i = 0; i < 4; i++) {
        float4 uu = u4[i * 64 + lane];
        fx4 pv;
        pv.x = ex[i * 4 + 0] * inv;
        pv.y = ex[i * 4 + 1] * inv;
        pv.z = ex[i * 4 + 2] * inv;
        pv.w = ex[i * 4 + 3] * inv;
        __builtin_nontemporal_store(pv, &p4[i * 64 + lane]);
        float us[4] = {uu.x, uu.y, uu.z, uu.w};
#pragma unroll
        for (int j = 0; j < 4; j++) {
            const int idx = i * 4 + j;
            bool keep = x[idx] >= kthf;
            float lp = keep ? (x[idx] - mlz) : -INFINITY;
            float g = -__logf(-__logf(us[j] + 1e-20f) + 1e-20f);
            float sc = lp + g;
            int v = i * 256 + lane * 4 + j;
            if (sc > bestv) { bestv = sc; besti = v; }   // strict >: earliest v in-lane
        }
    }
#pragma unroll
    for (int off = 32; off; off >>= 1) {
        float ov = __shfl_xor(bestv, off, 64);
        int   oi = __shfl_xor(besti, off, 64);
        if (ov > bestv || (ov == bestv && oi < besti)) { bestv = ov; besti = oi; }
    }
    if (lane == 0) samples[row] = besti;
}

// tokens[b*D + d] = (d==0 || samples[b]==NOTE_TYPE) ? samples[d*B+b] : 0
__global__ __launch_bounds__(256) void tokens_kernel(
    const int* __restrict__ samples, float* __restrict__ tokens_out)
{
    int i = blockIdx.x * 256 + threadIdx.x;   // exactly B*D threads
    int b = i >> 3;
    int d = i & 7;
    int sm = samples[d * BB + b];
    int t0 = samples[b];
    tokens_out[i] = (d == 0 || t0 == 1) ? (float)sm : 0.0f;
}

extern "C" void kernel_launch(void* const* d_in, const int* in_sizes, int n_in,
                              void* d_out, int out_size, void* d_ws, size_t ws_size,
                              hipStream_t stream) {
    const float* logits = (const float*)d_in[0];
    const float* unoise = (const float*)d_in[1];
    const int*   curvals = (const int*)d_in[2];

    float* out        = (float*)d_out;
    float* tokens_out = out;                       // [B*D]
    float* probs_out  = out + (size_t)BB * DD;     // [D*B*V]
    int*   samples    = (int*)d_ws;                // [D*B]

    decode_row_kernel<<<(DD * BB) / RPB, 256, 0, stream>>>(logits, unoise, curvals,
                                                           probs_out, samples);
    tokens_kernel<<<(BB * DD) / 256, 256, 0, stream>>>(samples, tokens_out);
}